// Round 9
// baseline (1030.232 us; speedup 1.0000x reference)
//
#include <hip/hip_runtime.h>
#include <math.h>

#define BB 4
#define NN 2048              // N == M
#define TPB 256
#define ROWS 16              // rows owned per block
#define GRPS 16              // column groups (grp = tid>>4)
#define CPG (NN/GRPS)        // 128 columns per group, stride GRPS
#define BPB (NN/ROWS)        // 128 blocks per batch
#define NBLK (BB*BPB)        // 512 blocks = exactly 2 per CU
#define SLOT (BB*NN)         // 8192

#if __has_builtin(__builtin_amdgcn_exp2f)
  #define FEXP2(x) __builtin_amdgcn_exp2f(x)
#else
  #define FEXP2(x) exp2f(x)
#endif
#if __has_builtin(__builtin_amdgcn_sqrtf)
  #define FSQRT(x) __builtin_amdgcn_sqrtf(x)
#else
  #define FSQRT(x) sqrtf(x)
#endif

// ws float layout:
// [0]       ratL  [SLOT]
// [SLOT]    ratR  [SLOT]
// [2*SLOT]  remR  [SLOT]
// [3*SLOT]  costp [NBLK]
// [3*SLOT+NBLK] barrier region, 288 uints:
//    sub[i] at [i*16] (16 counters, own cacheline), root at [256], gen at [272]
#define BAR_WORDS 288

__global__ void k_init_bar(float* __restrict__ ws) {
    unsigned* bar = (unsigned*)(ws + 3*SLOT + NBLK);
    if (threadIdx.x < BAR_WORDS) bar[threadIdx.x] = 0u;
}

// Hierarchical grid barrier: 512 arrivals -> 16 sub-counters(32 each) -> root(16) -> gen++
__device__ __forceinline__ void gsync(unsigned* bar, unsigned& tgt, int bid, int tid) {
    __syncthreads();
    if (tid == 0) {
        __threadfence();                      // release: flush writes (agent scope)
        ++tgt;
        unsigned old = __hip_atomic_fetch_add(&bar[(bid & 15) << 4], 1u,
                            __ATOMIC_ACQ_REL, __HIP_MEMORY_SCOPE_AGENT);
        if (((old + 1u) & 31u) == 0u) {       // last of this sub-group of 32
            unsigned r = __hip_atomic_fetch_add(&bar[256], 1u,
                            __ATOMIC_ACQ_REL, __HIP_MEMORY_SCOPE_AGENT);
            if (((r + 1u) & 15u) == 0u)       // last sub-group
                __hip_atomic_fetch_add(&bar[272], 1u,
                            __ATOMIC_ACQ_REL, __HIP_MEMORY_SCOPE_AGENT);
        }
        while (__hip_atomic_load(&bar[272], __ATOMIC_ACQUIRE,
                                 __HIP_MEMORY_SCOPE_AGENT) < tgt)
            __builtin_amdgcn_s_sleep(1);
        __threadfence();                      // acquire: invalidate stale cache
    }
    __syncthreads();
}

#define ROW_REDUCE(v, red)                                        \
    do {                                                          \
        (v) += __shfl_xor((v), 16, 64);                           \
        (v) += __shfl_xor((v), 32, 64);                           \
        if ((tid & 63) < 16) red[tid >> 6][tid & 15] = (v);       \
    } while (0)

__global__ void __launch_bounds__(TPB, 2)
k_emd(const float* __restrict__ tpl, const float* __restrict__ src,
      float* __restrict__ ws, float* __restrict__ out) {
    __shared__ float tx[NN], ty[NN], tz[NN];     // template points
    __shared__ float sxx[NN], syy[NN], szz[NN];  // source points
    __shared__ float wA[NN], wB[NN];             // per-phase weights
    __shared__ float redr[4][ROWS], redc[4][ROWS], reda[4][ROWS];

    float* ratL  = ws;
    float* ratR  = ws + SLOT;
    float* remRg = ws + 2*SLOT;
    float* costp = ws + 3*SLOT;
    unsigned* bar = (unsigned*)(ws + 3*SLOT + NBLK);

    const int bid = blockIdx.x, tid = threadIdx.x;
    const int b = bid / BPB, rc = bid % BPB;
    const int row = tid & 15, grp = tid >> 4;
    const int gbase = b*NN;
    const int ownt = gbase + rc*ROWS + tid;      // owner-thread (tid<16) global idx

    // stage both point sets once
    for (int i = tid; i < NN; i += TPB) {
        const float* tp = tpl + (gbase + i)*3;
        tx[i] = tp[0]; ty[i] = tp[1]; tz[i] = tp[2];
        const float* sp = src + (gbase + i)*3;
        sxx[i] = sp[0]; syy[i] = sp[1]; szz[i] = sp[2];
    }
    __syncthreads();

    const float pxA = tx[rc*ROWS + row], pyA = ty[rc*ROWS + row], pzA = tz[rc*ROWS + row];
    const float pxB = sxx[rc*ROWS + row], pyB = syy[rc*ROWS + row], pzB = szz[rc*ROWS + row];

    const float L2E = 1.4426950408889634f;
    unsigned tgt = 0;
    float remL_reg = 1.0f, remR_reg = 1.0f, ratL_reg = 0.0f, costacc = 0.0f;

    // ---- Phase A0: ratL(0) = 1/(sum_m exp2(l0*d2) + 1e-9), weights = 1
    {
        const float lv = -L2E * 16384.0f;
        float a0 = 0.f, a1 = 0.f;
#pragma unroll 8
        for (int i = 0; i < CPG; i += 2) {
            int i0 = grp + (i << 4), i1 = i0 + GRPS;
            float dx0 = pxA - sxx[i0], dy0 = pyA - syy[i0], dz0 = pzA - szz[i0];
            float dx1 = pxA - sxx[i1], dy1 = pyA - syy[i1], dz1 = pzA - szz[i1];
            a0 += FEXP2(lv*(dx0*dx0 + dy0*dy0 + dz0*dz0));
            a1 += FEXP2(lv*(dx1*dx1 + dy1*dy1 + dz1*dz1));
        }
        float a = a0 + a1;
        ROW_REDUCE(a, reda);
        __syncthreads();
        if (tid < ROWS) {
            float t = reda[0][tid] + reda[1][tid] + reda[2][tid] + reda[3][tid];
            ratL_reg = 1.0f / (t + 1e-9f);
            ratL[ownt] = ratL_reg;
        }
    }
    gsync(bar, tgt, bid, tid);

    for (int k = 0; k < 10; ++k) {
        const float lvC = (k == 9) ? 0.0f : -L2E * exp2f((float)(14 - 2*k));

        // ---- B(k): sumr[m] = sum_n exp2(lvC*d2)*ratL[n] -> ratR, remR update
        for (int i = tid; i < NN; i += TPB) wA[i] = ratL[gbase + i];
        __syncthreads();
        {
            float a0 = 0.f, a1 = 0.f;
#pragma unroll 8
            for (int i = 0; i < CPG; i += 2) {
                int i0 = grp + (i << 4), i1 = i0 + GRPS;
                float dx0 = tx[i0]-pxB, dy0 = ty[i0]-pyB, dz0 = tz[i0]-pzB;
                float dx1 = tx[i1]-pxB, dy1 = ty[i1]-pyB, dz1 = tz[i1]-pzB;
                a0 += FEXP2(lvC*(dx0*dx0 + dy0*dy0 + dz0*dz0)) * wA[i0];
                a1 += FEXP2(lvC*(dx1*dx1 + dy1*dy1 + dz1*dz1)) * wA[i1];
            }
            float a = a0 + a1;
            ROW_REDUCE(a, reda);
            __syncthreads();
            if (tid < ROWS) {
                float t = reda[0][tid] + reda[1][tid] + reda[2][tid] + reda[3][tid];
                float rt = remR_reg / (t + 1e-9f);
                ratR[ownt] = rt;
                remR_reg = fmaxf(remR_reg - rt*t, 0.0f);  // colsum = ratioR*sumr
                remRg[ownt] = remR_reg;
            }
        }
        gsync(bar, tgt, bid, tid);

        if (k < 9) {
            // ---- CA: C(k) {rowsum->remL, cost} fused with A(k+1) {->ratL}
            const float lvA = (k == 8) ? 0.0f : -L2E * exp2f((float)(12 - 2*k));
            for (int i = tid; i < NN; i += TPB) {
                wA[i] = ratR[gbase + i];
                wB[i] = remRg[gbase + i];
            }
            __syncthreads();
            float r0 = 0.f, r1 = 0.f, c0 = 0.f, c1 = 0.f, a0 = 0.f, a1 = 0.f;
#pragma unroll 4
            for (int i = 0; i < CPG; i += 2) {
                int i0 = grp + (i << 4), i1 = i0 + GRPS;
                float dx0 = pxA - sxx[i0], dy0 = pyA - syy[i0], dz0 = pzA - szz[i0];
                float dx1 = pxA - sxx[i1], dy1 = pyA - syy[i1], dz1 = pzA - szz[i1];
                float d20 = dx0*dx0 + dy0*dy0 + dz0*dz0;
                float d21 = dx1*dx1 + dy1*dy1 + dz1*dz1;
                float t0 = FEXP2(lvC*d20) * wA[i0];
                float t1 = FEXP2(lvC*d21) * wA[i1];
                r0 += t0; r1 += t1;
                c0 += t0 * FSQRT(fmaxf(d20, 1e-24f));
                c1 += t1 * FSQRT(fmaxf(d21, 1e-24f));
                a0 += FEXP2(lvA*d20) * wB[i0];
                a1 += FEXP2(lvA*d21) * wB[i1];
            }
            float r = r0 + r1, c = c0 + c1, a = a0 + a1;
            ROW_REDUCE(r, redr);
            ROW_REDUCE(c, redc);
            ROW_REDUCE(a, reda);
            __syncthreads();
            if (tid < ROWS) {
                float rt = redr[0][tid] + redr[1][tid] + redr[2][tid] + redr[3][tid];
                float ct = redc[0][tid] + redc[1][tid] + redc[2][tid] + redc[3][tid];
                float at = reda[0][tid] + reda[1][tid] + reda[2][tid] + reda[3][tid];
                float rlt = ratL_reg;                     // ratioL at level k
                costacc += rlt * ct;
                remL_reg = fmaxf(remL_reg - rlt*rt, 0.0f);
                ratL_reg = remL_reg / (at + 1e-9f);       // ratioL at level k+1
                ratL[ownt] = ratL_reg;
            }
            gsync(bar, tgt, bid, tid);
        } else {
            // ---- C9 (level 0): cost only; w0 = 1
            for (int i = tid; i < NN; i += TPB) wA[i] = ratR[gbase + i];
            __syncthreads();
            float c0 = 0.f, c1 = 0.f;
#pragma unroll 8
            for (int i = 0; i < CPG; i += 2) {
                int i0 = grp + (i << 4), i1 = i0 + GRPS;
                float dx0 = pxA - sxx[i0], dy0 = pyA - syy[i0], dz0 = pzA - szz[i0];
                float dx1 = pxA - sxx[i1], dy1 = pyA - syy[i1], dz1 = pzA - szz[i1];
                float d20 = dx0*dx0 + dy0*dy0 + dz0*dz0;
                float d21 = dx1*dx1 + dy1*dy1 + dz1*dz1;
                c0 += wA[i0] * FSQRT(fmaxf(d20, 1e-24f));
                c1 += wA[i1] * FSQRT(fmaxf(d21, 1e-24f));
            }
            float c = c0 + c1;
            ROW_REDUCE(c, redc);
            __syncthreads();
            if (tid < ROWS) {
                float ct = redc[0][tid] + redc[1][tid] + redc[2][tid] + redc[3][tid];
                costacc += ratL_reg * ct;
            }
        }
    }

    // per-block cost -> costp[bid]
    {
        float v = costacc;    // nonzero only in lanes 0..15 of wave 0
#pragma unroll
        for (int off = 8; off > 0; off >>= 1) v += __shfl_xor(v, off, 16);
        if (tid == 0) costp[bid] = v;
    }
    gsync(bar, tgt, bid, tid);

    // block 0 reduces all partials
    if (bid == 0) {
        float t = 0.f;
        for (int i = tid; i < NBLK; i += TPB) t += costp[i];
#pragma unroll
        for (int off = 32; off > 0; off >>= 1) t += __shfl_down(t, off, 64);
        if ((tid & 63) == 0) redr[0][tid >> 6] = t;
        __syncthreads();
        if (tid == 0)
            out[0] = (redr[0][0] + redr[0][1] + redr[0][2] + redr[0][3])
                     * (1.0f / (float)(BB * NN));
    }
}

extern "C" void kernel_launch(void* const* d_in, const int* in_sizes, int n_in,
                              void* d_out, int out_size, void* d_ws, size_t ws_size,
                              hipStream_t stream) {
    const float* tpl = (const float*)d_in[0];
    const float* src = (const float*)d_in[1];
    float* ws = (float*)d_ws;
    float* out = (float*)d_out;

    k_init_bar<<<1, 512, 0, stream>>>(ws);
    k_emd<<<NBLK, TPB, 0, stream>>>(tpl, src, ws, out);
}

// Round 10
// 388.488 us; speedup vs baseline: 2.6519x; 2.6519x over previous
//
#include <hip/hip_runtime.h>
#include <math.h>

#define BB 4
#define NN 2048              // N == M
#define TPB 256
#define ROWS 16              // rows per block (row = tid&15)
#define GRPS 16              // column groups (grp = tid>>4)
#define CPG (NN/GRPS)        // 128 cols per group, stride GRPS
#define CPT (NN/TPB)         // 8 cols per thread in sweep2
#define BPB (NN/ROWS)        // 128 blocks (strips) per batch
#define NBLK (BB*BPB)        // 512 blocks
#define SLOT (BB*NN)         // 8192
#define POFF (4*SLOT)                 // partials P[b][strip][m]
#define COFF (POFF + BB*BPB*NN)       // costp[NBLK]

#if __has_builtin(__builtin_amdgcn_exp2f)
  #define FEXP2(x) __builtin_amdgcn_exp2f(x)
#else
  #define FEXP2(x) exp2f(x)
#endif
#if __has_builtin(__builtin_amdgcn_sqrtf)
  #define FSQRT(x) __builtin_amdgcn_sqrtf(x)
#else
  #define FSQRT(x) sqrtf(x)
#endif

// ws float layout:
// [0]      ratL [SLOT]   (per template row, written by owning block)
// [SLOT]   remL [SLOT]
// [2*SLOT] ratR [SLOT]   (per source col, written by k_Y)
// [3*SLOT] remR [SLOT]
// [POFF]   P    [BB][BPB][NN]  per-strip column partials
// [COFF]   costp[NBLK]

#define ROW_REDUCE(v, red)                                        \
    do {                                                          \
        (v) += __shfl_xor((v), 16, 64);                           \
        (v) += __shfl_xor((v), 32, 64);                           \
        if ((tid & 63) < 16) red[tid >> 6][tid & 15] = (v);       \
    } while (0)

// X0: suml(0) with weights 1 -> ratL(0); sweep2 -> P(0).
__global__ void k_X0(const float* __restrict__ tpl, const float* __restrict__ src,
                     float* __restrict__ ws, float lvl) {
    __shared__ float4 sh4[NN];          // src {x,y,z,-}
    __shared__ float4 shtp[ROWS];       // own tpl points, .w = ratL after reduce
    __shared__ float red[4][ROWS];
    int bid = blockIdx.x, tid = threadIdx.x;
    int b = bid / BPB, rc = bid % BPB;
    int row = tid & 15, grp = tid >> 4;
    int gbase = b*NN;
    float* ratL = ws;
    for (int i = tid; i < NN; i += TPB) {
        const float* sp = src + (gbase + i)*3;
        sh4[i] = make_float4(sp[0], sp[1], sp[2], 0.0f);
    }
    if (tid < ROWS) {
        const float* tp = tpl + (gbase + rc*ROWS + tid)*3;
        shtp[tid] = make_float4(tp[0], tp[1], tp[2], 0.0f);
    }
    __syncthreads();
    float px = shtp[row].x, py = shtp[row].y, pz = shtp[row].z;
    float a0 = 0.f, a1 = 0.f;
#pragma unroll 8
    for (int i = 0; i < CPG; i += 2) {
        int i0 = grp + (i << 4), i1 = i0 + GRPS;
        float4 s0 = sh4[i0], s1 = sh4[i1];
        float dx0 = px-s0.x, dy0 = py-s0.y, dz0 = pz-s0.z;
        float dx1 = px-s1.x, dy1 = py-s1.y, dz1 = pz-s1.z;
        a0 += FEXP2(lvl*(dx0*dx0 + dy0*dy0 + dz0*dz0));
        a1 += FEXP2(lvl*(dx1*dx1 + dy1*dy1 + dz1*dz1));
    }
    float a = a0 + a1;
    ROW_REDUCE(a, red);
    __syncthreads();
    if (tid < ROWS) {
        float t = red[0][tid] + red[1][tid] + red[2][tid] + red[3][tid];
        float rl = 1.0f / (t + 1e-9f);
        ratL[gbase + rc*ROWS + tid] = rl;
        shtp[tid].w = rl;
    }
    __syncthreads();
    // sweep2: P[b][rc][m] = sum_{own rows} exp2(lvl*d2)*ratL
    float* P = ws + POFF + (size_t)(b*BPB + rc)*NN;
#pragma unroll
    for (int i = 0; i < CPT; ++i) {
        int m = tid + (i << 8);
        float4 s = sh4[m];
        float acc = 0.f;
#pragma unroll 4
        for (int r = 0; r < ROWS; ++r) {
            float4 t = shtp[r];
            float dx = t.x-s.x, dy = t.y-s.y, dz = t.z-s.z;
            acc += FEXP2(lvl*(dx*dx + dy*dy + dz*dz)) * t.w;
        }
        P[m] = acc;
    }
}

// Y: sumr[m] = sum_strips P[.][m] -> ratR, remR update. 32 blocks.
__global__ void k_Y(float* __restrict__ ws, int first) {
    int gm = blockIdx.x * TPB + threadIdx.x;     // [0, SLOT)
    int b = gm >> 11, m = gm & (NN - 1);
    float* ratR = ws + 2*SLOT;
    float* remR = ws + 3*SLOT;
    const float* P = ws + POFF + (size_t)(b*BPB)*NN + m;
    float s = 0.f;
#pragma unroll 8
    for (int st = 0; st < BPB; ++st) s += P[(size_t)st*NN];
    float rr = first ? 1.0f : remR[gm];
    float rt = rr / (s + 1e-9f);
    ratR[gm] = rt;
    remR[gm] = fmaxf(rr - rt*s, 0.0f);           // colsum = ratioR*sumr_raw
}

// X(j), j=1..9: finish level j-1 (rowsum+cost -> remL) and start level j
// (suml -> ratL(j), sweep2 -> P(j)).
__global__ void k_X(const float* __restrict__ tpl, const float* __restrict__ src,
                    float* __restrict__ ws, float lvlPrev, float lvlCur, int first) {
    __shared__ float4 sh4[NN];          // src {x,y,z, ratR}
    __shared__ float  shw[NN];          // remR (post Y(j-1))
    __shared__ float4 shtp[ROWS];       // own tpl points, .w = ratL(j) after reduce
    __shared__ float redr[4][ROWS], redc[4][ROWS], reda[4][ROWS];
    int bid = blockIdx.x, tid = threadIdx.x;
    int b = bid / BPB, rc = bid % BPB;
    int row = tid & 15, grp = tid >> 4;
    int gbase = b*NN;
    float* ratL = ws;
    float* remL = ws + SLOT;
    const float* ratR = ws + 2*SLOT;
    const float* remR = ws + 3*SLOT;
    float* costp = ws + COFF;
    for (int i = tid; i < NN; i += TPB) {
        const float* sp = src + (gbase + i)*3;
        sh4[i] = make_float4(sp[0], sp[1], sp[2], ratR[gbase + i]);
        shw[i] = remR[gbase + i];
    }
    if (tid < ROWS) {
        const float* tp = tpl + (gbase + rc*ROWS + tid)*3;
        shtp[tid] = make_float4(tp[0], tp[1], tp[2], 0.0f);
    }
    __syncthreads();
    float px = shtp[row].x, py = shtp[row].y, pz = shtp[row].z;
    float r0 = 0.f, r1 = 0.f, c0 = 0.f, c1 = 0.f, a0 = 0.f, a1 = 0.f;
#pragma unroll 4
    for (int i = 0; i < CPG; i += 2) {
        int i0 = grp + (i << 4), i1 = i0 + GRPS;
        float4 s0 = sh4[i0], s1 = sh4[i1];
        float w0 = shw[i0], w1 = shw[i1];
        float dx0 = px-s0.x, dy0 = py-s0.y, dz0 = pz-s0.z;
        float dx1 = px-s1.x, dy1 = py-s1.y, dz1 = pz-s1.z;
        float d20 = dx0*dx0 + dy0*dy0 + dz0*dz0;
        float d21 = dx1*dx1 + dy1*dy1 + dz1*dz1;
        float t0 = FEXP2(lvlPrev*d20) * s0.w;
        float t1 = FEXP2(lvlPrev*d21) * s1.w;
        r0 += t0; r1 += t1;
        c0 += t0 * FSQRT(fmaxf(d20, 1e-24f));
        c1 += t1 * FSQRT(fmaxf(d21, 1e-24f));
        a0 += FEXP2(lvlCur*d20) * w0;
        a1 += FEXP2(lvlCur*d21) * w1;
    }
    float r = r0 + r1, c = c0 + c1, a = a0 + a1;
    ROW_REDUCE(r, redr);
    ROW_REDUCE(c, redc);
    ROW_REDUCE(a, reda);
    __syncthreads();
    if (tid < ROWS) {
        float rt = redr[0][tid] + redr[1][tid] + redr[2][tid] + redr[3][tid];
        float ct = redc[0][tid] + redc[1][tid] + redc[2][tid] + redc[3][tid];
        float at = reda[0][tid] + reda[1][tid] + reda[2][tid] + reda[3][tid];
        int g = gbase + rc*ROWS + tid;
        float rlRat = ratL[g];                        // ratioL at level j-1
        float rlv = first ? 1.0f : remL[g];
        float rlnew = fmaxf(rlv - rlRat*rt, 0.0f);
        remL[g] = rlnew;
        float ratLnew = rlnew / (at + 1e-9f);         // ratioL at level j
        ratL[g] = ratLnew;
        shtp[tid].w = ratLnew;
        float v = rlRat * ct;                         // cost partial (level j-1)
#pragma unroll
        for (int off = 8; off > 0; off >>= 1) v += __shfl_xor(v, off, 16);
        if (tid == 0) costp[bid] = first ? v : costp[bid] + v;
    }
    __syncthreads();
    // sweep2: P(j)[b][rc][m]
    float* P = ws + POFF + (size_t)(b*BPB + rc)*NN;
#pragma unroll
    for (int i = 0; i < CPT; ++i) {
        int m = tid + (i << 8);
        float4 s = sh4[m];
        float acc = 0.f;
#pragma unroll 4
        for (int r2 = 0; r2 < ROWS; ++r2) {
            float4 t = shtp[r2];
            float dx = t.x-s.x, dy = t.y-s.y, dz = t.z-s.z;
            acc += FEXP2(lvlCur*(dx*dx + dy*dy + dz*dz)) * t.w;
        }
        P[m] = acc;
    }
}

// X10: finish level 9 (lvl=0 -> w0=1): cost only.
__global__ void k_X10(const float* __restrict__ tpl, const float* __restrict__ src,
                      float* __restrict__ ws) {
    __shared__ float4 sh4[NN];          // src {x,y,z, ratR}
    __shared__ float4 shtp[ROWS];
    __shared__ float redc[4][ROWS];
    int bid = blockIdx.x, tid = threadIdx.x;
    int b = bid / BPB, rc = bid % BPB;
    int row = tid & 15, grp = tid >> 4;
    int gbase = b*NN;
    const float* ratL = ws;
    const float* ratR = ws + 2*SLOT;
    float* costp = ws + COFF;
    for (int i = tid; i < NN; i += TPB) {
        const float* sp = src + (gbase + i)*3;
        sh4[i] = make_float4(sp[0], sp[1], sp[2], ratR[gbase + i]);
    }
    if (tid < ROWS) {
        const float* tp = tpl + (gbase + rc*ROWS + tid)*3;
        shtp[tid] = make_float4(tp[0], tp[1], tp[2], 0.0f);
    }
    __syncthreads();
    float px = shtp[row].x, py = shtp[row].y, pz = shtp[row].z;
    float c0 = 0.f, c1 = 0.f;
#pragma unroll 8
    for (int i = 0; i < CPG; i += 2) {
        int i0 = grp + (i << 4), i1 = i0 + GRPS;
        float4 s0 = sh4[i0], s1 = sh4[i1];
        float dx0 = px-s0.x, dy0 = py-s0.y, dz0 = pz-s0.z;
        float dx1 = px-s1.x, dy1 = py-s1.y, dz1 = pz-s1.z;
        float d20 = dx0*dx0 + dy0*dy0 + dz0*dz0;
        float d21 = dx1*dx1 + dy1*dy1 + dz1*dz1;
        c0 += s0.w * FSQRT(fmaxf(d20, 1e-24f));
        c1 += s1.w * FSQRT(fmaxf(d21, 1e-24f));
    }
    float c = c0 + c1;
    ROW_REDUCE(c, redc);
    __syncthreads();
    if (tid < ROWS) {
        float ct = redc[0][tid] + redc[1][tid] + redc[2][tid] + redc[3][tid];
        float v = ratL[gbase + rc*ROWS + tid] * ct;
#pragma unroll
        for (int off = 8; off > 0; off >>= 1) v += __shfl_xor(v, off, 16);
        if (tid == 0) costp[bid] += v;
    }
}

__global__ void k_final(const float* __restrict__ ws, float* __restrict__ out) {
    __shared__ float swv[4];
    const float* costp = ws + COFF;
    int tid = threadIdx.x;
    float t = 0.f;
    for (int i = tid; i < NBLK; i += TPB) t += costp[i];
#pragma unroll
    for (int off = 32; off > 0; off >>= 1) t += __shfl_down(t, off, 64);
    if ((tid & 63) == 0) swv[tid >> 6] = t;
    __syncthreads();
    if (tid == 0) out[0] = (swv[0] + swv[1] + swv[2] + swv[3]) * (1.0f / (float)(BB * NN));
}

extern "C" void kernel_launch(void* const* d_in, const int* in_sizes, int n_in,
                              void* d_out, int out_size, void* d_ws, size_t ws_size,
                              hipStream_t stream) {
    const float* tpl = (const float*)d_in[0];
    const float* src = (const float*)d_in[1];
    float* ws = (float*)d_ws;
    float* out = (float*)d_out;

    // lvl2[k] = level_k * log2(e); levels = -4^(7-k) for k=0..8, 0 for k=9
    const double L2E = 1.4426950408889634;
    float lvl2[10];
    for (int k = 0; k < 9; ++k) lvl2[k] = (float)(-pow(4.0, 7 - k) * L2E);
    lvl2[9] = 0.0f;

    k_X0<<<NBLK, TPB, 0, stream>>>(tpl, src, ws, lvl2[0]);
    for (int k = 0; k < 9; ++k) {
        k_Y<<<SLOT/TPB, TPB, 0, stream>>>(ws, k == 0 ? 1 : 0);
        k_X<<<NBLK, TPB, 0, stream>>>(tpl, src, ws, lvl2[k], lvl2[k+1], k == 0 ? 1 : 0);
    }
    k_Y<<<SLOT/TPB, TPB, 0, stream>>>(ws, 0);
    k_X10<<<NBLK, TPB, 0, stream>>>(tpl, src, ws);
    k_final<<<1, TPB, 0, stream>>>(ws, out);
}

// Round 11
// 307.421 us; speedup vs baseline: 3.3512x; 1.2637x over previous
//
#include <hip/hip_runtime.h>
#include <math.h>

#define BB 4
#define NN 2048              // N == M
#define TPB 256
#define ROWS 4               // rows per block, one per wave
#define BPB (NN/ROWS)        // 512 blocks per batch
#define NBLK (BB*BPB)        // 2048 blocks
#define SLOT (BB*NN)         // 8192
#define CPL 32               // columns per lane (64 lanes * 32 = 2048)

#if __has_builtin(__builtin_amdgcn_exp2f)
  #define FEXP2(x) __builtin_amdgcn_exp2f(x)
#else
  #define FEXP2(x) exp2f(x)
#endif
#if __has_builtin(__builtin_amdgcn_sqrtf)
  #define FSQRT(x) __builtin_amdgcn_sqrtf(x)
#else
  #define FSQRT(x) sqrtf(x)
#endif

// ws float layout:
// [0]       ratL  [SLOT]
// [SLOT]    remL  [SLOT]
// [2*SLOT]  ratR  [SLOT]
// [3*SLOT]  remR  [SLOT]
// [4*SLOT]  costw [NBLK*4]   per-wave cost partials (accumulated over levels)

__device__ __forceinline__ float wsum(float v) {
#pragma unroll
    for (int off = 32; off > 0; off >>= 1) v += __shfl_xor(v, off, 64);
    return v;
}

// A0: ratL(0)[n] = 1/(sum_m exp2(lvl*d2)+1e-9); zero costw.
__global__ void __launch_bounds__(TPB, 4)
k_A0(const float* __restrict__ tpl, const float* __restrict__ src,
     float* __restrict__ ws, float lvl) {
    int bid = blockIdx.x, tid = threadIdx.x;
    int b = bid / BPB, rc = bid % BPB;
    int wv = tid >> 6, lane = tid & 63;
    int gbase = b*NN, n = rc*ROWS + wv;
    const float* tp = tpl + (gbase + n)*3;
    float px = tp[0], py = tp[1], pz = tp[2];
    const float* sp = src + (size_t)gbase*3;
    float a0 = 0.f, a1 = 0.f;
#pragma unroll 8
    for (int i = 0; i < CPL; i += 2) {
        int c0 = (lane + (i << 6))*3, c1 = c0 + 192;
        float dx0 = px-sp[c0], dy0 = py-sp[c0+1], dz0 = pz-sp[c0+2];
        float dx1 = px-sp[c1], dy1 = py-sp[c1+1], dz1 = pz-sp[c1+2];
        a0 += FEXP2(lvl*(dx0*dx0 + dy0*dy0 + dz0*dz0));
        a1 += FEXP2(lvl*(dx1*dx1 + dy1*dy1 + dz1*dz1));
    }
    float a = wsum(a0 + a1);
    if (lane == 0) {
        ws[gbase + n] = 1.0f / (a + 1e-9f);       // ratL
        ws[4*SLOT + bid*4 + wv] = 0.0f;           // costw
    }
}

// B(k), k=0..8: sumr[m] = sum_n exp2(lvl*d2)*ratL[n] -> ratR, remR update.
__global__ void __launch_bounds__(TPB, 4)
k_B(const float* __restrict__ tpl, const float* __restrict__ src,
    float* __restrict__ ws, float lvl, int first) {
    __shared__ float wL[NN];
    int bid = blockIdx.x, tid = threadIdx.x;
    int b = bid / BPB, rc = bid % BPB;
    int wv = tid >> 6, lane = tid & 63;
    int gbase = b*NN, m = rc*ROWS + wv;
    const float* ratL = ws;
    float* ratR = ws + 2*SLOT;
    float* remR = ws + 3*SLOT;
    for (int i = tid; i < NN; i += TPB) wL[i] = ratL[gbase + i];
    __syncthreads();
    const float* sp = src + (gbase + m)*3;
    float px = sp[0], py = sp[1], pz = sp[2];
    const float* tp = tpl + (size_t)gbase*3;
    float a0 = 0.f, a1 = 0.f;
#pragma unroll 8
    for (int i = 0; i < CPL; i += 2) {
        int n0 = lane + (i << 6), n1 = n0 + 64;
        int c0 = n0*3, c1 = c0 + 192;
        float dx0 = tp[c0]-px, dy0 = tp[c0+1]-py, dz0 = tp[c0+2]-pz;
        float dx1 = tp[c1]-px, dy1 = tp[c1+1]-py, dz1 = tp[c1+2]-pz;
        a0 += FEXP2(lvl*(dx0*dx0 + dy0*dy0 + dz0*dz0)) * wL[n0];
        a1 += FEXP2(lvl*(dx1*dx1 + dy1*dy1 + dz1*dz1)) * wL[n1];
    }
    float a = wsum(a0 + a1);
    if (lane == 0) {
        int g = gbase + m;
        float rr = first ? 1.0f : remR[g];
        float rt = rr / (a + 1e-9f);
        ratR[g] = rt;
        remR[g] = fmaxf(rr - rt*a, 0.0f);  // colsum = ratioR*sumr_raw (exact)
    }
}

// CA(k), k=0..7: C(k) {rowsum->remL, cost} + A(k+1) {suml->ratL}.
// lvlC = 4*lvlA, so w0C = (eA^2)^2 with eA = exp2(lvlA*d2): ONE exp per pair.
__global__ void __launch_bounds__(TPB, 4)
k_CA(const float* __restrict__ tpl, const float* __restrict__ src,
     float* __restrict__ ws, float lvlA, int first) {
    __shared__ float wR[NN], wM[NN];
    int bid = blockIdx.x, tid = threadIdx.x;
    int b = bid / BPB, rc = bid % BPB;
    int wv = tid >> 6, lane = tid & 63;
    int gbase = b*NN, n = rc*ROWS + wv;
    float* ratL = ws;
    float* remL = ws + SLOT;
    const float* ratR = ws + 2*SLOT;
    const float* remR = ws + 3*SLOT;
    float* costw = ws + 4*SLOT;
    for (int i = tid; i < NN; i += TPB) {
        wR[i] = ratR[gbase + i];
        wM[i] = remR[gbase + i];
    }
    __syncthreads();
    const float* tp = tpl + (gbase + n)*3;
    float px = tp[0], py = tp[1], pz = tp[2];
    const float* sp = src + (size_t)gbase*3;
    float r0 = 0.f, r1 = 0.f, c0a = 0.f, c1a = 0.f, a0 = 0.f, a1 = 0.f;
#pragma unroll 4
    for (int i = 0; i < CPL; i += 2) {
        int m0 = lane + (i << 6), m1 = m0 + 64;
        int c0 = m0*3, c1 = c0 + 192;
        float dx0 = px-sp[c0], dy0 = py-sp[c0+1], dz0 = pz-sp[c0+2];
        float dx1 = px-sp[c1], dy1 = py-sp[c1+1], dz1 = pz-sp[c1+2];
        float d20 = dx0*dx0 + dy0*dy0 + dz0*dz0;
        float d21 = dx1*dx1 + dy1*dy1 + dz1*dz1;
        float eA0 = FEXP2(lvlA*d20), eA1 = FEXP2(lvlA*d21);
        float sq0 = eA0*eA0, sq1 = eA1*eA1;
        float t0 = (sq0*sq0) * wR[m0];       // exp2(lvlC*d2)*ratR, lvlC=4*lvlA
        float t1 = (sq1*sq1) * wR[m1];
        r0 += t0; r1 += t1;
        c0a += t0 * FSQRT(fmaxf(d20, 1e-24f));
        c1a += t1 * FSQRT(fmaxf(d21, 1e-24f));
        a0 += eA0 * wM[m0];
        a1 += eA1 * wM[m1];
    }
    float r = wsum(r0 + r1), c = wsum(c0a + c1a), a = wsum(a0 + a1);
    if (lane == 0) {
        int g = gbase + n;
        float rlRat = ratL[g];                    // ratioL at level k
        float rl = first ? 1.0f : remL[g];
        float rlnew = fmaxf(rl - rlRat*r, 0.0f);
        remL[g] = rlnew;
        ratL[g] = rlnew / (a + 1e-9f);            // ratioL at level k+1
        costw[bid*4 + wv] += rlRat * c;
    }
}

// CA8: C(8) {w0 = exp2(lvl8*d2)} + A(9) {lvl=0 -> suml = sum(remR) = Rtot}.
__global__ void __launch_bounds__(TPB, 4)
k_CA8(const float* __restrict__ tpl, const float* __restrict__ src,
      float* __restrict__ ws, float lvlC) {
    __shared__ float wR[NN], wM[NN];
    __shared__ float srt[4];
    int bid = blockIdx.x, tid = threadIdx.x;
    int b = bid / BPB, rc = bid % BPB;
    int wv = tid >> 6, lane = tid & 63;
    int gbase = b*NN, n = rc*ROWS + wv;
    float* ratL = ws;
    float* remL = ws + SLOT;
    const float* ratR = ws + 2*SLOT;
    const float* remR = ws + 3*SLOT;
    float* costw = ws + 4*SLOT;
    float part = 0.f;
    for (int i = tid; i < NN; i += TPB) {
        wR[i] = ratR[gbase + i];
        float v = remR[gbase + i];
        wM[i] = v;
        part += v;
    }
    part = wsum(part);
    if ((tid & 63) == 0) srt[tid >> 6] = part;
    __syncthreads();
    float Rtot = srt[0] + srt[1] + srt[2] + srt[3];
    const float* tp = tpl + (gbase + n)*3;
    float px = tp[0], py = tp[1], pz = tp[2];
    const float* sp = src + (size_t)gbase*3;
    float r0 = 0.f, r1 = 0.f, c0a = 0.f, c1a = 0.f;
#pragma unroll 8
    for (int i = 0; i < CPL; i += 2) {
        int m0 = lane + (i << 6), m1 = m0 + 64;
        int c0 = m0*3, c1 = c0 + 192;
        float dx0 = px-sp[c0], dy0 = py-sp[c0+1], dz0 = pz-sp[c0+2];
        float dx1 = px-sp[c1], dy1 = py-sp[c1+1], dz1 = pz-sp[c1+2];
        float d20 = dx0*dx0 + dy0*dy0 + dz0*dz0;
        float d21 = dx1*dx1 + dy1*dy1 + dz1*dz1;
        float t0 = FEXP2(lvlC*d20) * wR[m0];
        float t1 = FEXP2(lvlC*d21) * wR[m1];
        r0 += t0; r1 += t1;
        c0a += t0 * FSQRT(fmaxf(d20, 1e-24f));
        c1a += t1 * FSQRT(fmaxf(d21, 1e-24f));
    }
    float r = wsum(r0 + r1), c = wsum(c0a + c1a);
    if (lane == 0) {
        int g = gbase + n;
        float rlRat = ratL[g];
        float rlnew = fmaxf(remL[g] - rlRat*r, 0.0f);
        remL[g] = rlnew;
        ratL[g] = rlnew / (Rtot + 1e-9f);         // ratioL at level 9
        costw[bid*4 + wv] += rlRat * c;
    }
}

// C9 (level 9, lvl=0): sumr = sum(ratL9) = Stot (B9 folded in);
// cost += ratL9[n] * invS * sum_m remR[m]*dist.
__global__ void __launch_bounds__(TPB, 4)
k_C9(const float* __restrict__ tpl, const float* __restrict__ src,
     float* __restrict__ ws) {
    __shared__ float wM[NN];
    __shared__ float srt[4];
    int bid = blockIdx.x, tid = threadIdx.x;
    int b = bid / BPB, rc = bid % BPB;
    int wv = tid >> 6, lane = tid & 63;
    int gbase = b*NN, n = rc*ROWS + wv;
    const float* ratL = ws;
    const float* remR = ws + 3*SLOT;
    float* costw = ws + 4*SLOT;
    float part = 0.f;
    for (int i = tid; i < NN; i += TPB) {
        wM[i] = remR[gbase + i];
        part += ratL[gbase + i];
    }
    part = wsum(part);
    if ((tid & 63) == 0) srt[tid >> 6] = part;
    __syncthreads();
    float invS = 1.0f / (srt[0] + srt[1] + srt[2] + srt[3] + 1e-9f);
    const float* tp = tpl + (gbase + n)*3;
    float px = tp[0], py = tp[1], pz = tp[2];
    const float* sp = src + (size_t)gbase*3;
    float c0a = 0.f, c1a = 0.f;
#pragma unroll 8
    for (int i = 0; i < CPL; i += 2) {
        int m0 = lane + (i << 6), m1 = m0 + 64;
        int c0 = m0*3, c1 = c0 + 192;
        float dx0 = px-sp[c0], dy0 = py-sp[c0+1], dz0 = pz-sp[c0+2];
        float dx1 = px-sp[c1], dy1 = py-sp[c1+1], dz1 = pz-sp[c1+2];
        float d20 = dx0*dx0 + dy0*dy0 + dz0*dz0;
        float d21 = dx1*dx1 + dy1*dy1 + dz1*dz1;
        c0a += wM[m0] * FSQRT(fmaxf(d20, 1e-24f));
        c1a += wM[m1] * FSQRT(fmaxf(d21, 1e-24f));
    }
    float c = wsum(c0a + c1a);
    if (lane == 0)
        costw[bid*4 + wv] += ratL[gbase + n] * invS * c;
}

// Final: reduce NBLK*4 per-wave partials, scale.
__global__ void k_final(const float* __restrict__ ws, float* __restrict__ out) {
    __shared__ float swv[4];
    const float* costw = ws + 4*SLOT;
    int tid = threadIdx.x;
    float t = 0.f;
    for (int i = tid; i < NBLK*4; i += TPB) t += costw[i];
#pragma unroll
    for (int off = 32; off > 0; off >>= 1) t += __shfl_down(t, off, 64);
    if ((tid & 63) == 0) swv[tid >> 6] = t;
    __syncthreads();
    if (tid == 0) out[0] = (swv[0] + swv[1] + swv[2] + swv[3]) * (1.0f / (float)(BB * NN));
}

extern "C" void kernel_launch(void* const* d_in, const int* in_sizes, int n_in,
                              void* d_out, int out_size, void* d_ws, size_t ws_size,
                              hipStream_t stream) {
    const float* tpl = (const float*)d_in[0];
    const float* src = (const float*)d_in[1];
    float* ws = (float*)d_ws;
    float* out = (float*)d_out;

    // lvl2[k] = level_k * log2(e); levels = -4^(7-k) for k=0..8, 0 for k=9
    const double L2E = 1.4426950408889634;
    float lvl2[10];
    for (int k = 0; k < 9; ++k) lvl2[k] = (float)(-pow(4.0, 7 - k) * L2E);
    lvl2[9] = 0.0f;

    k_A0<<<NBLK, TPB, 0, stream>>>(tpl, src, ws, lvl2[0]);
    for (int k = 0; k < 8; ++k) {
        k_B <<<NBLK, TPB, 0, stream>>>(tpl, src, ws, lvl2[k], k == 0 ? 1 : 0);
        k_CA<<<NBLK, TPB, 0, stream>>>(tpl, src, ws, lvl2[k+1], k == 0 ? 1 : 0);
    }
    k_B  <<<NBLK, TPB, 0, stream>>>(tpl, src, ws, lvl2[8], 0);
    k_CA8<<<NBLK, TPB, 0, stream>>>(tpl, src, ws, lvl2[8]);
    k_C9 <<<NBLK, TPB, 0, stream>>>(tpl, src, ws);
    k_final<<<1, TPB, 0, stream>>>(ws, out);
}